// Round 7
// baseline (47384.616 us; speedup 1.0000x reference)
//
#include <hip/hip_runtime.h>
#include <math.h>

#define NUM_CODE 256
#define CODE_DIM 128
#define HALF_DIM 64
#define N_LAYERS 5
#define TT 8192
#define MTOK 131072
#define MARGIN 1e-4f

#define QOFF   0ull
#define IOFF   83886080ull              // 16*128*8192*5
#define PPLOFF 84541440ull
#define LOSSOFF 84541445ull

// ws: [0,5120) u32 cnt[5][256]; [5120,5160) double loss[5]; [5160,10280) float ee2[5][256]
//
// Numeric model (CONFIRMED r6): dot_c / ee2_c = numpy pairwise-8 mul/add trees;
// dist = fl(fl(rr2+ee2_c) - fl(2*dot_c)); argmin first-min; residual fl32 subtract.
// This round keeps decisions bitwise-identical via fast-FMA filter + exact recheck
// (margin 1e-4 >> worst-case 1.6e-5 chain divergence).

__global__ __launch_bounds__(256) void rvq_init_kernel(
        const float* __restrict__ emb,
        unsigned int* __restrict__ cnt,
        double* __restrict__ lossws,
        float* __restrict__ ee2)
{
    int g = blockIdx.x * 256 + threadIdx.x;
    if (g < N_LAYERS) lossws[g] = 0.0;
    if (g < N_LAYERS * NUM_CODE) {
        cnt[g] = 0u;
        const float* e = emb + (size_t)g * CODE_DIM;
        float s[8];
        #pragma unroll
        for (int j = 0; j < 8; ++j) s[j] = __fmul_rn(e[j], e[j]);
        #pragma unroll
        for (int i = 8; i < CODE_DIM; i += 8) {
            #pragma unroll
            for (int j = 0; j < 8; ++j)
                s[j] = __fadd_rn(s[j], __fmul_rn(e[i + j], e[i + j]));
        }
        ee2[g] = __fadd_rn(
            __fadd_rn(__fadd_rn(s[0], s[1]), __fadd_rn(s[2], s[3])),
            __fadd_rn(__fadd_rn(s[4], s[5]), __fadd_rn(s[6], s[7])));
    }
}

// Cooperative exact dist for code c: thread pair (lane, lane^1) holds dim halves.
// Pass 1: standalone partial chains over my half (terms ascending d, k%8 chains).
// Exchange; pass 2: append my products onto partner partials (valid on the h=1
// lane, whose prefix is h=0's low half); tree; pull result from lane|1.
__device__ __forceinline__ float exact_di_coop(
        const float* __restrict__ erow_half,   // el + c*128 + D0
        const float r[HALF_DIM], float t1, int lane)
{
    float s[8];
    {
        const float4* ev = reinterpret_cast<const float4*>(erow_half);
        #pragma unroll
        for (int blk = 0; blk < 16; ++blk) {
            float4 e = ev[blk];
            const int j0 = (blk & 1) * 4;
            float p0 = __fmul_rn(r[4*blk+0], e.x);
            float p1 = __fmul_rn(r[4*blk+1], e.y);
            float p2 = __fmul_rn(r[4*blk+2], e.z);
            float p3 = __fmul_rn(r[4*blk+3], e.w);
            if (blk < 2) { s[j0+0]=p0; s[j0+1]=p1; s[j0+2]=p2; s[j0+3]=p3; }
            else {
                s[j0+0] = __fadd_rn(s[j0+0], p0);
                s[j0+1] = __fadd_rn(s[j0+1], p1);
                s[j0+2] = __fadd_rn(s[j0+2], p2);
                s[j0+3] = __fadd_rn(s[j0+3], p3);
            }
        }
    }
    float f[8];
    #pragma unroll
    for (int j = 0; j < 8; ++j) f[j] = __shfl_xor(s[j], 1, 64);
    {
        const volatile float* ev = erow_half;   // force reload (cap reg spike)
        #pragma unroll
        for (int blk = 0; blk < 16; ++blk) {
            const int j0 = (blk & 1) * 4;
            float e0 = ev[4*blk+0], e1 = ev[4*blk+1];
            float e2 = ev[4*blk+2], e3 = ev[4*blk+3];
            f[j0+0] = __fadd_rn(f[j0+0], __fmul_rn(r[4*blk+0], e0));
            f[j0+1] = __fadd_rn(f[j0+1], __fmul_rn(r[4*blk+1], e1));
            f[j0+2] = __fadd_rn(f[j0+2], __fmul_rn(r[4*blk+2], e2));
            f[j0+3] = __fadd_rn(f[j0+3], __fmul_rn(r[4*blk+3], e3));
        }
    }
    float dot = __fadd_rn(
        __fadd_rn(__fadd_rn(f[0], f[1]), __fadd_rn(f[2], f[3])),
        __fadd_rn(__fadd_rn(f[4], f[5]), __fadd_rn(f[6], f[7])));
    float di = __fsub_rn(t1, __fadd_rn(dot, dot));
    return __shfl(di, lane | 1, 64);
}

__global__ __launch_bounds__(256, 4) void rvq_main_kernel(
        const float* __restrict__ x,
        const float* __restrict__ emb,
        float* __restrict__ out,
        unsigned int* __restrict__ cnt,
        double* __restrict__ lossws,
        const float* __restrict__ ee2ws)
{
    const int tid  = threadIdx.x;
    const int lane = tid & 63;
    const int gid  = blockIdx.x * 256 + tid;
    const int m    = gid >> 1;            // token
    const int h    = gid & 1;             // dim half
    const int b    = m >> 13;
    const int t    = m & (TT - 1);
    const size_t xb = (size_t)b * (CODE_DIM * (size_t)TT) + (size_t)t;
    const int D0 = h * HALF_DIM;

    float r[HALF_DIM];
    #pragma unroll
    for (int i = 0; i < HALF_DIM; ++i)
        r[i] = x[xb + (size_t)(D0 + i) * TT];

    float* __restrict__ outq = out + QOFF;
    float* __restrict__ outi = out + IOFF;

    int hist[N_LAYERS];

    for (int l = 0; l < N_LAYERS; ++l) {
        const float* __restrict__ el  = emb + (size_t)l * NUM_CODE * CODE_DIM;
        const float* __restrict__ e2l = ee2ws + l * NUM_CODE;

        // ---- rr2: cooperative exact pairwise-8 over full 128 dims ----
        float rr2;
        {
            float s[8];
            #pragma unroll
            for (int blk = 0; blk < 16; ++blk) {
                const int j0 = (blk & 1) * 4;
                float p0 = __fmul_rn(r[4*blk+0], r[4*blk+0]);
                float p1 = __fmul_rn(r[4*blk+1], r[4*blk+1]);
                float p2 = __fmul_rn(r[4*blk+2], r[4*blk+2]);
                float p3 = __fmul_rn(r[4*blk+3], r[4*blk+3]);
                if (blk < 2) { s[j0+0]=p0; s[j0+1]=p1; s[j0+2]=p2; s[j0+3]=p3; }
                else {
                    s[j0+0] = __fadd_rn(s[j0+0], p0);
                    s[j0+1] = __fadd_rn(s[j0+1], p1);
                    s[j0+2] = __fadd_rn(s[j0+2], p2);
                    s[j0+3] = __fadd_rn(s[j0+3], p3);
                }
            }
            float f[8];
            #pragma unroll
            for (int j = 0; j < 8; ++j) f[j] = __shfl_xor(s[j], 1, 64);
            #pragma unroll
            for (int blk = 0; blk < 16; ++blk) {
                const int j0 = (blk & 1) * 4;
                f[j0+0] = __fadd_rn(f[j0+0], __fmul_rn(r[4*blk+0], r[4*blk+0]));
                f[j0+1] = __fadd_rn(f[j0+1], __fmul_rn(r[4*blk+1], r[4*blk+1]));
                f[j0+2] = __fadd_rn(f[j0+2], __fmul_rn(r[4*blk+2], r[4*blk+2]));
                f[j0+3] = __fadd_rn(f[j0+3], __fmul_rn(r[4*blk+3], r[4*blk+3]));
            }
            float tr = __fadd_rn(
                __fadd_rn(__fadd_rn(f[0], f[1]), __fadd_rn(f[2], f[3])),
                __fadd_rn(__fadd_rn(f[4], f[5]), __fadd_rn(f[6], f[7])));
            rr2 = __shfl(tr, lane | 1, 64);
        }

        // ---- fast filter: FMA partial dot over my half + cross-pair add ----
        float minfast = INFINITY;
        int ci0=0, ci1=0, ci2=0, ci3=0;
        float cf0=0.f, cf1=0.f, cf2=0.f, cf3=0.f;
        int ccnt = 0;
        for (int c = 0; c < NUM_CODE; ++c) {
            const float4* ep = reinterpret_cast<const float4*>(
                el + (size_t)c * CODE_DIM + D0);
            float a0 = 0.f, a1 = 0.f, a2 = 0.f, a3 = 0.f;
            #pragma unroll
            for (int d = 0; d < 16; ++d) {
                float4 e = ep[d];
                a0 = fmaf(r[4*d+0], e.x, a0);
                a1 = fmaf(r[4*d+1], e.y, a1);
                a2 = fmaf(r[4*d+2], e.z, a2);
                a3 = fmaf(r[4*d+3], e.w, a3);
            }
            float mine = (a0 + a1) + (a2 + a3);
            float dot  = __fadd_rn(mine, __shfl_xor(mine, 1, 64)); // commutative -> pair-identical
            float di   = __fsub_rn(__fadd_rn(rr2, e2l[c]), __fadd_rn(dot, dot));
            if (di < minfast + MARGIN) {
                if      (ccnt == 0) { ci0 = c; cf0 = di; }
                else if (ccnt == 1) { ci1 = c; cf1 = di; }
                else if (ccnt == 2) { ci2 = c; cf2 = di; }
                else if (ccnt == 3) { ci3 = c; cf3 = di; }
                ++ccnt;
            }
            minfast = fminf(minfast, di);
        }

        // ---- exact selection among candidates (ascending c, strict <) ----
        const float thrF = minfast + MARGIN;
        int bi = 0; float bestex = INFINITY;
        if (ccnt > 4) {
            for (int c = 0; c < NUM_CODE; ++c) {
                float t1 = __fadd_rn(rr2, e2l[c]);
                float ex = exact_di_coop(el + (size_t)c * CODE_DIM + D0, r, t1, lane);
                if (ex < bestex) { bestex = ex; bi = c; }
            }
        } else {
            if (ccnt > 0 && cf0 < thrF) {
                float t1 = __fadd_rn(rr2, e2l[ci0]);
                float ex = exact_di_coop(el + (size_t)ci0 * CODE_DIM + D0, r, t1, lane);
                if (ex < bestex) { bestex = ex; bi = ci0; }
            }
            if (ccnt > 1 && cf1 < thrF) {
                float t1 = __fadd_rn(rr2, e2l[ci1]);
                float ex = exact_di_coop(el + (size_t)ci1 * CODE_DIM + D0, r, t1, lane);
                if (ex < bestex) { bestex = ex; bi = ci1; }
            }
            if (ccnt > 2 && cf2 < thrF) {
                float t1 = __fadd_rn(rr2, e2l[ci2]);
                float ex = exact_di_coop(el + (size_t)ci2 * CODE_DIM + D0, r, t1, lane);
                if (ex < bestex) { bestex = ex; bi = ci2; }
            }
            if (ccnt > 3 && cf3 < thrF) {
                float t1 = __fadd_rn(rr2, e2l[ci3]);
                float ex = exact_di_coop(el + (size_t)ci3 * CODE_DIM + D0, r, t1, lane);
                if (ex < bestex) { bestex = ex; bi = ci3; }
            }
        }

        hist[l] = bi;
        if (h == 0) {
            outi[(size_t)m * N_LAYERS + l] = (float)bi;
            atomicAdd(&cnt[l * NUM_CODE + bi], 1u);
        }

        // ---- residual update (my half): r = fl(r - e[bi]) ----
        const float4* q4 = reinterpret_cast<const float4*>(
            el + (size_t)bi * CODE_DIM + D0);
        #pragma unroll
        for (int d = 0; d < 16; ++d) {
            float4 qv = q4[d];
            r[4*d+0] = __fsub_rn(r[4*d+0], qv.x);
            r[4*d+1] = __fsub_rn(r[4*d+1], qv.y);
            r[4*d+2] = __fsub_rn(r[4*d+2], qv.z);
            r[4*d+3] = __fsub_rn(r[4*d+3], qv.w);
        }

        // ---- latent loss term (f64, wave-reduced; halves sum correctly) ----
        double ls = 0.0;
        #pragma unroll
        for (int i = 0; i < HALF_DIM; ++i)
            ls = fma((double)r[i], (double)r[i], ls);
        for (int o = 32; o > 0; o >>= 1)
            ls += __shfl_down(ls, o, 64);
        if (lane == 0) atomicAdd(&lossws[l], ls);
    }

    // ---------------- Phase B: quantized output (no LDS) ----------------
    const float* prow[N_LAYERS];
    #pragma unroll
    for (int l = 0; l < N_LAYERS; ++l)
        prow[l] = emb + ((size_t)l * NUM_CODE + hist[l]) * CODE_DIM + D0;

    for (int cc = 0; cc < 16; ++cc) {
        float4 q[N_LAYERS];
        #pragma unroll
        for (int l = 0; l < N_LAYERS; ++l)
            q[l] = reinterpret_cast<const float4*>(prow[l])[cc];
        #pragma unroll
        for (int i = 0; i < 4; ++i) {
            int nn = D0 + 4*cc + i;
            float xv = x[xb + (size_t)nn * TT];
            float rr = xv;
            size_t base = (xb + (size_t)nn * TT) * N_LAYERS;
            #pragma unroll
            for (int l = 0; l < N_LAYERS; ++l) {
                float qi = (i == 0) ? q[l].x : (i == 1) ? q[l].y
                         : (i == 2) ? q[l].z : q[l].w;
                rr = __fsub_rn(rr, qi);
                outq[base + l] = __fsub_rn(xv, rr);
            }
        }
    }
}

__global__ __launch_bounds__(256) void rvq_finalize_kernel(
        const unsigned int* __restrict__ cnt,
        const double* __restrict__ lossws,
        float* __restrict__ out)
{
    __shared__ double sd[256];
    const int k = threadIdx.x;
    const double epsf = 1.1920928955078125e-07;  // float32 eps
    for (int l = 0; l < N_LAYERS; ++l) {
        float p = (float)cnt[l * NUM_CODE + k] / 131072.0f;   // exact (/2^17)
        double term = (double)p * log((double)p + epsf);
        sd[k] = term;
        __syncthreads();
        for (int s = 128; s > 0; s >>= 1) {
            if (k < s) sd[k] += sd[k + s];
            __syncthreads();
        }
        if (k == 0) out[PPLOFF + l] = (float)exp(-sd[0]);
        __syncthreads();
    }
    if (k == 0) {
        double tot = 0.0;
        for (int l = 0; l < N_LAYERS; ++l) tot += lossws[l];
        out[LOSSOFF] = (float)(tot / 16777216.0);   // / (B*N*T)
    }
}

extern "C" void kernel_launch(void* const* d_in, const int* in_sizes, int n_in,
                              void* d_out, int out_size, void* d_ws, size_t ws_size,
                              hipStream_t stream)
{
    const float* x   = (const float*)d_in[0];
    const float* emb = (const float*)d_in[1];
    float* out = (float*)d_out;

    unsigned int* cnt = (unsigned int*)d_ws;
    double* lossws    = (double*)((char*)d_ws + 5120);
    float* ee2ws      = (float*)((char*)d_ws + 5160);

    rvq_init_kernel<<<5, 256, 0, stream>>>(emb, cnt, lossws, ee2ws);
    rvq_main_kernel<<<(2 * MTOK) / 256, 256, 0, stream>>>(x, emb, out, cnt, lossws, ee2ws);
    rvq_finalize_kernel<<<1, 256, 0, stream>>>(cnt, lossws, out);
}

// Round 8
// 5060.447 us; speedup vs baseline: 9.3637x; 9.3637x over previous
//
#include <hip/hip_runtime.h>
#include <math.h>

#define NUM_CODE 256
#define CODE_DIM 128
#define HALF_DIM 64
#define N_LAYERS 5
#define TT 8192
#define MTOK 131072
#define MARGIN 3e-5f

#define QOFF   0ull
#define IOFF   83886080ull              // 16*128*8192*5
#define PPLOFF 84541440ull
#define LOSSOFF 84541445ull

// ws: [0,5120) u32 cnt[5][256]; [5120,5160) double loss[5]; [5160,10280) float ee2[5][256]
//
// Numeric model (CONFIRMED r6, machinery VALIDATED r7): dot_c / ee2_c = numpy
// pairwise-8 mul/add trees; dist = fl(fl(rr2+ee2_c) - fl(2*dot_c)); argmin
// first-min; residual fl32 subtract. Fast fmaf filter decides outright when
// the fast top-2 gap >= MARGIN (13-sigma safe); near-ties resolved by the
// bitwise-exact cooperative chain. Top-3 tracking bounds the 3-way-tie risk:
// full exact scan when m3-m1 < MARGIN (P~3.5e-4).

__global__ __launch_bounds__(256) void rvq_init_kernel(
        const float* __restrict__ emb,
        unsigned int* __restrict__ cnt,
        double* __restrict__ lossws,
        float* __restrict__ ee2)
{
    int g = blockIdx.x * 256 + threadIdx.x;
    if (g < N_LAYERS) lossws[g] = 0.0;
    if (g < N_LAYERS * NUM_CODE) {
        cnt[g] = 0u;
        const float* e = emb + (size_t)g * CODE_DIM;
        float s[8];
        #pragma unroll
        for (int j = 0; j < 8; ++j) s[j] = __fmul_rn(e[j], e[j]);
        #pragma unroll
        for (int i = 8; i < CODE_DIM; i += 8) {
            #pragma unroll
            for (int j = 0; j < 8; ++j)
                s[j] = __fadd_rn(s[j], __fmul_rn(e[i + j], e[i + j]));
        }
        ee2[g] = __fadd_rn(
            __fadd_rn(__fadd_rn(s[0], s[1]), __fadd_rn(s[2], s[3])),
            __fadd_rn(__fadd_rn(s[4], s[5]), __fadd_rn(s[6], s[7])));
    }
}

// Cooperative exact dist for one code: pair (lane, lane^1) holds dim halves.
// Pass 1: standalone pairwise-8 partials over my half. Exchange; pass 2:
// append my products onto partner partials (valid on h=1 lane, whose prefix
// is h=0's low half); tree; broadcast from lane|1. Validated in r7.
__device__ __forceinline__ float exact_di_coop(
        const float* __restrict__ erow_half,   // el + c*128 + D0
        const float r[HALF_DIM], float t1, int lane)
{
    float s[8];
    {
        const float4* ev = reinterpret_cast<const float4*>(erow_half);
        #pragma unroll
        for (int blk = 0; blk < 16; ++blk) {
            float4 e = ev[blk];
            const int j0 = (blk & 1) * 4;
            float p0 = __fmul_rn(r[4*blk+0], e.x);
            float p1 = __fmul_rn(r[4*blk+1], e.y);
            float p2 = __fmul_rn(r[4*blk+2], e.z);
            float p3 = __fmul_rn(r[4*blk+3], e.w);
            if (blk < 2) { s[j0+0]=p0; s[j0+1]=p1; s[j0+2]=p2; s[j0+3]=p3; }
            else {
                s[j0+0] = __fadd_rn(s[j0+0], p0);
                s[j0+1] = __fadd_rn(s[j0+1], p1);
                s[j0+2] = __fadd_rn(s[j0+2], p2);
                s[j0+3] = __fadd_rn(s[j0+3], p3);
            }
        }
    }
    float f[8];
    #pragma unroll
    for (int j = 0; j < 8; ++j) f[j] = __shfl_xor(s[j], 1, 64);
    {
        const float4* ev = reinterpret_cast<const float4*>(erow_half);
        #pragma unroll
        for (int blk = 0; blk < 16; ++blk) {
            float4 e = ev[blk];
            const int j0 = (blk & 1) * 4;
            f[j0+0] = __fadd_rn(f[j0+0], __fmul_rn(r[4*blk+0], e.x));
            f[j0+1] = __fadd_rn(f[j0+1], __fmul_rn(r[4*blk+1], e.y));
            f[j0+2] = __fadd_rn(f[j0+2], __fmul_rn(r[4*blk+2], e.z));
            f[j0+3] = __fadd_rn(f[j0+3], __fmul_rn(r[4*blk+3], e.w));
        }
    }
    float dot = __fadd_rn(
        __fadd_rn(__fadd_rn(f[0], f[1]), __fadd_rn(f[2], f[3])),
        __fadd_rn(__fadd_rn(f[4], f[5]), __fadd_rn(f[6], f[7])));
    float di = __fsub_rn(t1, __fadd_rn(dot, dot));
    return __shfl(di, lane | 1, 64);
}

__global__ __launch_bounds__(256, 4) void rvq_main_kernel(
        const float* __restrict__ x,
        const float* __restrict__ emb,
        float* __restrict__ out,
        unsigned int* __restrict__ cnt,
        double* __restrict__ lossws,
        const float* __restrict__ ee2ws)
{
    const int tid  = threadIdx.x;
    const int lane = tid & 63;
    const int gid  = blockIdx.x * 256 + tid;
    const int m    = gid >> 1;            // token
    const int h    = gid & 1;             // dim half
    const int b    = m >> 13;
    const int t    = m & (TT - 1);
    const size_t xb = (size_t)b * (CODE_DIM * (size_t)TT) + (size_t)t;
    const int D0 = h * HALF_DIM;

    float r[HALF_DIM];
    #pragma unroll
    for (int i = 0; i < HALF_DIM; ++i)
        r[i] = x[xb + (size_t)(D0 + i) * TT];

    float* __restrict__ outq = out + QOFF;
    float* __restrict__ outi = out + IOFF;

    int hist[N_LAYERS];

    for (int l = 0; l < N_LAYERS; ++l) {
        const float* __restrict__ el  = emb + (size_t)l * NUM_CODE * CODE_DIM;
        const float* __restrict__ e2l = ee2ws + l * NUM_CODE;

        // ---- rr2: cooperative exact pairwise-8 over full 128 dims ----
        float rr2;
        {
            float s[8];
            #pragma unroll
            for (int blk = 0; blk < 16; ++blk) {
                const int j0 = (blk & 1) * 4;
                float p0 = __fmul_rn(r[4*blk+0], r[4*blk+0]);
                float p1 = __fmul_rn(r[4*blk+1], r[4*blk+1]);
                float p2 = __fmul_rn(r[4*blk+2], r[4*blk+2]);
                float p3 = __fmul_rn(r[4*blk+3], r[4*blk+3]);
                if (blk < 2) { s[j0+0]=p0; s[j0+1]=p1; s[j0+2]=p2; s[j0+3]=p3; }
                else {
                    s[j0+0] = __fadd_rn(s[j0+0], p0);
                    s[j0+1] = __fadd_rn(s[j0+1], p1);
                    s[j0+2] = __fadd_rn(s[j0+2], p2);
                    s[j0+3] = __fadd_rn(s[j0+3], p3);
                }
            }
            float f[8];
            #pragma unroll
            for (int j = 0; j < 8; ++j) f[j] = __shfl_xor(s[j], 1, 64);
            #pragma unroll
            for (int blk = 0; blk < 16; ++blk) {
                const int j0 = (blk & 1) * 4;
                f[j0+0] = __fadd_rn(f[j0+0], __fmul_rn(r[4*blk+0], r[4*blk+0]));
                f[j0+1] = __fadd_rn(f[j0+1], __fmul_rn(r[4*blk+1], r[4*blk+1]));
                f[j0+2] = __fadd_rn(f[j0+2], __fmul_rn(r[4*blk+2], r[4*blk+2]));
                f[j0+3] = __fadd_rn(f[j0+3], __fmul_rn(r[4*blk+3], r[4*blk+3]));
            }
            float tr = __fadd_rn(
                __fadd_rn(__fadd_rn(f[0], f[1]), __fadd_rn(f[2], f[3])),
                __fadd_rn(__fadd_rn(f[4], f[5]), __fadd_rn(f[6], f[7])));
            rr2 = __shfl(tr, lane | 1, 64);
        }

        // ---- fast filter: FMA partial dot over my half + cross-pair add ----
        // Track top-3 minima (values) + top-2 indices, vs FINAL min semantics.
        float m1 = INFINITY, m2 = INFINITY, m3 = INFINITY;
        int i1 = 0, i2 = 0;
        for (int c = 0; c < NUM_CODE; ++c) {
            const float4* ep = reinterpret_cast<const float4*>(
                el + (size_t)c * CODE_DIM + D0);
            float a0 = 0.f, a1 = 0.f, a2 = 0.f, a3 = 0.f;
            #pragma unroll
            for (int d = 0; d < 16; ++d) {
                float4 e = ep[d];
                a0 = fmaf(r[4*d+0], e.x, a0);
                a1 = fmaf(r[4*d+1], e.y, a1);
                a2 = fmaf(r[4*d+2], e.z, a2);
                a3 = fmaf(r[4*d+3], e.w, a3);
            }
            float mine = (a0 + a1) + (a2 + a3);
            float dot  = __fadd_rn(mine, __shfl_xor(mine, 1, 64)); // commutative -> pair-identical
            float di   = __fsub_rn(__fadd_rn(rr2, e2l[c]), __fadd_rn(dot, dot));
            bool b1 = di < m1, b2 = di < m2, b3 = di < m3;
            m3 = b2 ? m2 : (b3 ? di : m3);
            m2 = b1 ? m1 : (b2 ? di : m2);
            i2 = b1 ? i1 : (b2 ? c  : i2);
            m1 = b1 ? di : m1;
            i1 = b1 ? c  : i1;
        }

        // ---- tiered exact resolution (pair-uniform branches) ----
        int bi = i1;
        if (m3 - m1 < MARGIN) {
            // 3-way near-tie (P~3.5e-4): full exact scan, first-min
            float best = INFINITY; int bidx = 0;
            for (int c = 0; c < NUM_CODE; ++c) {
                float t1 = __fadd_rn(rr2, e2l[c]);
                float ex = exact_di_coop(el + (size_t)c * CODE_DIM + D0, r, t1, lane);
                if (ex < best) { best = ex; bidx = c; }
            }
            bi = bidx;
        } else if (m2 - m1 < MARGIN) {
            // 2-way near-tie (~1%): exact compare of {i1,i2}, first-min
            int lo = min(i1, i2), hi = max(i1, i2);
            float exlo = exact_di_coop(el + (size_t)lo * CODE_DIM + D0, r,
                                       __fadd_rn(rr2, e2l[lo]), lane);
            float exhi = exact_di_coop(el + (size_t)hi * CODE_DIM + D0, r,
                                       __fadd_rn(rr2, e2l[hi]), lane);
            bi = (exhi < exlo) ? hi : lo;
        }

        hist[l] = bi;
        if (h == 0) {
            outi[(size_t)m * N_LAYERS + l] = (float)bi;
            atomicAdd(&cnt[l * NUM_CODE + bi], 1u);
        }

        // ---- residual update (my half): r = fl(r - e[bi]) ----
        const float4* q4 = reinterpret_cast<const float4*>(
            el + (size_t)bi * CODE_DIM + D0);
        #pragma unroll
        for (int d = 0; d < 16; ++d) {
            float4 qv = q4[d];
            r[4*d+0] = __fsub_rn(r[4*d+0], qv.x);
            r[4*d+1] = __fsub_rn(r[4*d+1], qv.y);
            r[4*d+2] = __fsub_rn(r[4*d+2], qv.z);
            r[4*d+3] = __fsub_rn(r[4*d+3], qv.w);
        }

        // ---- latent loss term (f64, wave-reduced; halves sum correctly) ----
        double ls = 0.0;
        #pragma unroll
        for (int i = 0; i < HALF_DIM; ++i)
            ls = fma((double)r[i], (double)r[i], ls);
        for (int o = 32; o > 0; o >>= 1)
            ls += __shfl_down(ls, o, 64);
        if (lane == 0) atomicAdd(&lossws[l], ls);
    }

    // ---------------- Phase B: quantized output (no LDS) ----------------
    // Dense v[5] per (n,t): 5 consecutive scalar stores (20B burst) avoids
    // the l-strided write amplification seen in r7.
    const float* prow[N_LAYERS];
    #pragma unroll
    for (int l = 0; l < N_LAYERS; ++l)
        prow[l] = emb + ((size_t)l * NUM_CODE + hist[l]) * CODE_DIM + D0;

    for (int cc = 0; cc < 16; ++cc) {
        float4 q[N_LAYERS];
        #pragma unroll
        for (int l = 0; l < N_LAYERS; ++l)
            q[l] = reinterpret_cast<const float4*>(prow[l])[cc];
        #pragma unroll
        for (int i = 0; i < 4; ++i) {
            int nn = D0 + 4*cc + i;
            float xv = x[xb + (size_t)nn * TT];
            float rr = xv;
            float v[N_LAYERS];
            #pragma unroll
            for (int l = 0; l < N_LAYERS; ++l) {
                float qi = (i == 0) ? q[l].x : (i == 1) ? q[l].y
                         : (i == 2) ? q[l].z : q[l].w;
                rr = __fsub_rn(rr, qi);
                v[l] = __fsub_rn(xv, rr);
            }
            size_t base = (xb + (size_t)nn * TT) * N_LAYERS;
            outq[base + 0] = v[0];
            outq[base + 1] = v[1];
            outq[base + 2] = v[2];
            outq[base + 3] = v[3];
            outq[base + 4] = v[4];
        }
    }
}

__global__ __launch_bounds__(256) void rvq_finalize_kernel(
        const unsigned int* __restrict__ cnt,
        const double* __restrict__ lossws,
        float* __restrict__ out)
{
    __shared__ double sd[256];
    const int k = threadIdx.x;
    const double epsf = 1.1920928955078125e-07;  // float32 eps
    for (int l = 0; l < N_LAYERS; ++l) {
        float p = (float)cnt[l * NUM_CODE + k] / 131072.0f;   // exact (/2^17)
        double term = (double)p * log((double)p + epsf);
        sd[k] = term;
        __syncthreads();
        for (int s = 128; s > 0; s >>= 1) {
            if (k < s) sd[k] += sd[k + s];
            __syncthreads();
        }
        if (k == 0) out[PPLOFF + l] = (float)exp(-sd[0]);
        __syncthreads();
    }
    if (k == 0) {
        double tot = 0.0;
        for (int l = 0; l < N_LAYERS; ++l) tot += lossws[l];
        out[LOSSOFF] = (float)(tot / 16777216.0);   // / (B*N*T)
    }
}

extern "C" void kernel_launch(void* const* d_in, const int* in_sizes, int n_in,
                              void* d_out, int out_size, void* d_ws, size_t ws_size,
                              hipStream_t stream)
{
    const float* x   = (const float*)d_in[0];
    const float* emb = (const float*)d_in[1];
    float* out = (float*)d_out;

    unsigned int* cnt = (unsigned int*)d_ws;
    double* lossws    = (double*)((char*)d_ws + 5120);
    float* ee2ws      = (float*)((char*)d_ws + 5160);

    rvq_init_kernel<<<5, 256, 0, stream>>>(emb, cnt, lossws, ee2ws);
    rvq_main_kernel<<<(2 * MTOK) / 256, 256, 0, stream>>>(x, emb, out, cnt, lossws, ee2ws);
    rvq_finalize_kernel<<<1, 256, 0, stream>>>(cnt, lossws, out);
}